// Round 3
// baseline (789.455 us; speedup 1.0000x reference)
//
#include <hip/hip_runtime.h>
#include <stdint.h>

#define B_   16
#define C_   512
#define H_   64
#define W_   64
#define NH_  8
#define HD_  64
#define HW_  4096

typedef __attribute__((ext_vector_type(8))) _Float16 f16x8;
typedef __attribute__((ext_vector_type(8))) unsigned short u16x8;
typedef __attribute__((ext_vector_type(4))) unsigned short u16x4;
typedef __attribute__((ext_vector_type(4))) float f32x4;

static __device__ __forceinline__ unsigned short f2h(float f) {
  _Float16 h = (_Float16)f;
  unsigned short u;
  __builtin_memcpy(&u, &h, 2);
  return u;
}
static __device__ __forceinline__ float h2f(unsigned short u) {
  _Float16 h;
  __builtin_memcpy(&h, &u, 2);
  return (float)h;
}

// ---------------- K0a: x (B,C,HW) fp32 -> xT (B,HW,C) f16 (transpose+convert)
__global__ __launch_bounds__(256) void rcca_tr(const float* __restrict__ x,
                                               unsigned short* __restrict__ xT) {
  __shared__ float lT[64 * 65];
  const int bid = blockIdx.x;
  const int st = bid & 63;          // hw tile
  const int ct = (bid >> 6) & 7;    // c tile
  const int b  = bid >> 9;
  const int t = threadIdx.x;
  const int hwl = t & 63;
  const int cl0 = (t >> 6) * 16;
  const float* src = x + ((size_t)(b * C_ + ct * 64 + cl0)) * HW_ + st * 64 + hwl;
#pragma unroll
  for (int jj = 0; jj < 16; ++jj)
    lT[(cl0 + jj) * 65 + hwl] = src[(size_t)jj * HW_];
  __syncthreads();
  const int hw2 = t >> 2;
  const int cc0 = (t & 3) * 16;
  u16x8 o0, o1;
#pragma unroll
  for (int u = 0; u < 8; ++u) {
    o0[u] = f2h(lT[(cc0 + u) * 65 + hw2]);
    o1[u] = f2h(lT[(cc0 + 8 + u) * 65 + hw2]);
  }
  unsigned short* dst = xT + ((size_t)b * HW_ + st * 64 + hw2) * C_ + ct * 64 + cc0;
  *(u16x8*)dst = o0;
  *(u16x8*)(dst + 8) = o1;
}

// ---------------- K0b: wq|wk|wv (512,512) fp32 -> Wc (1536,512) f16
__global__ __launch_bounds__(256) void rcca_cvtw(const float* __restrict__ wq,
                                                 const float* __restrict__ wk,
                                                 const float* __restrict__ wv,
                                                 unsigned short* __restrict__ Wc) {
  const int i = blockIdx.x * 256 + threadIdx.x;  // 196608 threads
  const int e = i * 4;
  const float* w = (e < 262144) ? wq : (e < 524288) ? wk : wv;
  const int off = e & 262143;
  const float4 v = *(const float4*)(w + off);
  u16x4 p;
  p[0] = f2h(v.x); p[1] = f2h(v.y); p[2] = f2h(v.z); p[3] = f2h(v.w);
  *(u16x4*)(Wc + e) = p;
}

// ---------------- Fused: per (b,h): QKV projection (MFMA, frags from global) +
// per-head attention + residual. 512 threads = 8 waves. Loop over 4 head-pairs.
// LDS: double-buffered-by-head {Q,K,VT} [64][72] f16; P overlays Q per head.
__global__ __launch_bounds__(512, 4) void rcca_fused(const unsigned short* __restrict__ xT,
                                                     const unsigned short* __restrict__ Wc,
                                                     const float* __restrict__ bq,
                                                     const float* __restrict__ bk,
                                                     const float* __restrict__ bv,
                                                     float* __restrict__ out) {
  __shared__ __align__(16) unsigned short smem[6 * 64 * 72];  // 55296 B
  unsigned short* buf[2][3];
  buf[0][0] = smem;                 // Q / P, head-local 0
  buf[0][1] = smem + 4608;          // K
  buf[0][2] = smem + 9216;          // V^T
  buf[1][0] = smem + 13824;
  buf[1][1] = smem + 18432;
  buf[1][2] = smem + 23040;

  const int bid = blockIdx.x;
  const int b = bid >> 6, h = bid & 63;
  const int t = threadIdx.x;
  const int wid = t >> 6, lane = t & 63, r = lane & 15, q = lane >> 4;
  const unsigned short* Aslice = xT + ((size_t)b * HW_ + h * 64) * C_;  // [w=64][c=512]

  const int mat = wid >> 1;      // 0=Q 1=K 2=V (waves 0..5)
  const int half = wid & 1;      // d-half (32)
  const float* biasm = (mat == 0) ? bq : (mat == 1) ? bk : bv;

  for (int hp = 0; hp < 4; ++hp) {
    // ================= GEMM phase: waves 0..5 compute QKV for heads hp*2, hp*2+1
    if (wid < 6) {
      f32x4 acc[4][4];
#pragma unroll
      for (int i = 0; i < 4; ++i)
#pragma unroll
        for (int j = 0; j < 4; ++j)
          acc[i][j] = (f32x4){0.f, 0.f, 0.f, 0.f};
      // B row base per j: mat*512 + (hp*2 + (j>>1))*64 + half*32 + (j&1)*16 + r
      const unsigned short* Brow[4];
#pragma unroll
      for (int j = 0; j < 4; ++j) {
        const int head = hp * 2 + (j >> 1);
        const int n = mat * 512 + head * 64 + half * 32 + (j & 1) * 16 + r;
        Brow[j] = Wc + (size_t)n * C_;
      }
      const unsigned short* Arow[4];
#pragma unroll
      for (int i = 0; i < 4; ++i)
        Arow[i] = Aslice + (size_t)(i * 16 + r) * C_;
#pragma unroll 4
      for (int kk = 0; kk < 16; ++kk) {
        const int k = kk * 32 + q * 8;
        f16x8 av[4], bw[4];
#pragma unroll
        for (int i = 0; i < 4; ++i) av[i] = *(const f16x8*)(Arow[i] + k);
#pragma unroll
        for (int j = 0; j < 4; ++j) bw[j] = *(const f16x8*)(Brow[j] + k);
#pragma unroll
        for (int i = 0; i < 4; ++i)
#pragma unroll
          for (int j = 0; j < 4; ++j)
            acc[i][j] = __builtin_amdgcn_mfma_f32_16x16x32_f16(av[i], bw[j], acc[i][j], 0, 0, 0);
      }
      // write results to LDS buffers (+bias). C layout: row m = i*16+q*4+reg, col n-part = j,r
#pragma unroll
      for (int j = 0; j < 4; ++j) {
        const int hl = j >> 1;
        const int d = half * 32 + (j & 1) * 16 + r;
        const int head = hp * 2 + hl;
        const float bias_v = biasm[head * 64 + d];
        if (mat < 2) {
          unsigned short* dst = buf[hl][mat];   // [w][d] stride 72
#pragma unroll
          for (int i = 0; i < 4; ++i)
#pragma unroll
            for (int reg = 0; reg < 4; ++reg)
              dst[(i * 16 + q * 4 + reg) * 72 + d] = f2h(acc[i][j][reg] + bias_v);
        } else {
          unsigned short* dst = buf[hl][2];     // V^T: [d][w] stride 72
#pragma unroll
          for (int i = 0; i < 4; ++i)
#pragma unroll
            for (int reg = 0; reg < 4; ++reg)
              dst[d * 72 + (i * 16 + q * 4 + reg)] = f2h(acc[i][j][reg] + bias_v);
        }
      }
    }
    __syncthreads();
    // ================= Attention phase: all 8 waves; wave -> (head-local, strip)
    {
      const int hl = wid >> 2;         // 0 or 1
      const int wv = wid & 3;          // 16-row strip
      const int head = hp * 2 + hl;
      unsigned short* sQ = buf[hl][0];
      unsigned short* sK = buf[hl][1];
      unsigned short* sVT = buf[hl][2];
      unsigned short* sP = sQ;         // overlay: each wave only touches its own strip rows
      f32x4 s[4];
#pragma unroll
      for (int j = 0; j < 4; ++j) s[j] = (f32x4){0.f, 0.f, 0.f, 0.f};
#pragma unroll
      for (int kk = 0; kk < 64; kk += 32) {
        f16x8 aq = *(const f16x8*)&sQ[(wv * 16 + r) * 72 + kk + q * 8];
#pragma unroll
        for (int j = 0; j < 4; ++j) {
          f16x8 bk8 = *(const f16x8*)&sK[(j * 16 + r) * 72 + kk + q * 8];
          s[j] = __builtin_amdgcn_mfma_f32_16x16x32_f16(aq, bk8, s[j], 0, 0, 0);
        }
      }
      float inv[4];
#pragma unroll
      for (int reg = 0; reg < 4; ++reg) {
        float mx = fmaxf(fmaxf(s[0][reg], s[1][reg]), fmaxf(s[2][reg], s[3][reg]));
#pragma unroll
        for (int o = 1; o < 16; o <<= 1) mx = fmaxf(mx, __shfl_xor(mx, o, 64));
        float p0 = __expf(s[0][reg] - mx);
        float p1 = __expf(s[1][reg] - mx);
        float p2 = __expf(s[2][reg] - mx);
        float p3 = __expf(s[3][reg] - mx);
        float sum = p0 + p1 + p2 + p3;
#pragma unroll
        for (int o = 1; o < 16; o <<= 1) sum += __shfl_xor(sum, o, 64);
        inv[reg] = 1.0f / sum;
        const int row = wv * 16 + q * 4 + reg;
        sP[row * 72 + 0 + r]  = f2h(p0);
        sP[row * 72 + 16 + r] = f2h(p1);
        sP[row * 72 + 32 + r] = f2h(p2);
        sP[row * 72 + 48 + r] = f2h(p3);
      }
      f32x4 o4[4];
#pragma unroll
      for (int j = 0; j < 4; ++j) o4[j] = (f32x4){0.f, 0.f, 0.f, 0.f};
#pragma unroll
      for (int kk = 0; kk < 64; kk += 32) {
        f16x8 ap = *(const f16x8*)&sP[(wv * 16 + r) * 72 + kk + q * 8];
#pragma unroll
        for (int jd = 0; jd < 4; ++jd) {
          f16x8 bv8 = *(const f16x8*)&sVT[(jd * 16 + r) * 72 + kk + q * 8];
          o4[jd] = __builtin_amdgcn_mfma_f32_16x16x32_f16(ap, bv8, o4[jd], 0, 0, 0);
        }
      }
      // epilogue: out[b][head*64+d][h][w] = O[w][d]*inv + f32(xT[b][h*64+w][head*64+d])
#pragma unroll
      for (int jd = 0; jd < 4; ++jd) {
        const int d = jd * 16 + r;
        const int c = head * 64 + d;
#pragma unroll
        for (int reg = 0; reg < 4; ++reg) {
          const int w = wv * 16 + q * 4 + reg;
          const float res = h2f(Aslice[(size_t)w * C_ + c]);
          out[((size_t)(b * C_ + c) * H_ + h) * W_ + w] = o4[jd][reg] * inv[reg] + res;
        }
      }
    }
    __syncthreads();  // buffers reusable by next head-pair
  }
}

extern "C" void kernel_launch(void* const* d_in, const int* in_sizes, int n_in,
                              void* d_out, int out_size, void* d_ws, size_t ws_size,
                              hipStream_t stream) {
  const float* x  = (const float*)d_in[0];
  const float* wq = (const float*)d_in[1];
  const float* bq = (const float*)d_in[2];
  const float* wk = (const float*)d_in[3];
  const float* bk = (const float*)d_in[4];
  const float* wv = (const float*)d_in[5];
  const float* bv = (const float*)d_in[6];
  float* out = (float*)d_out;
  char* ws = (char*)d_ws;
  // ws layout: xT 64 MiB | Wc 1.5 MiB
  unsigned short* xT = (unsigned short*)ws;
  unsigned short* Wc = (unsigned short*)(ws + (size_t)67108864);
  hipLaunchKernelGGL(rcca_tr,    dim3(8192), dim3(256), 0, stream, x, xT);
  hipLaunchKernelGGL(rcca_cvtw,  dim3(768),  dim3(256), 0, stream, wq, wk, wv, Wc);
  hipLaunchKernelGGL(rcca_fused, dim3(1024), dim3(512), 0, stream, xT, Wc, bq, bk, bv, out);
}